// Round 1
// baseline (303.738 us; speedup 1.0000x reference)
//
#include <hip/hip_runtime.h>

#define N_ 256
#define D_ 64
#define C_ 32
#define R_ 16
#define O_ 32

typedef _Float16 half8 __attribute__((ext_vector_type(8)));
typedef float f32x16 __attribute__((ext_vector_type(16)));

// Kernel 1: left/right prep. thread <-> (n,d,r). Reads fp32 (coalesced in 64B
// segments across r-lanes), computes max over i, writes exp(x-max) as fp16 in
// (d,r,n,i) layout (contiguous 64B per thread) + combined max sum.
__global__ __launch_bounds__(256) void prep_kernel(
    const float* __restrict__ left, const float* __restrict__ right,
    _Float16* __restrict__ lw, _Float16* __restrict__ rw,
    float* __restrict__ msum) {
  const int b = blockIdx.x, t = threadIdx.x;
  const int n = ((b >> 3) << 1) | (t >> 7);
  const int d = ((b & 7) << 3) | ((t >> 4) & 7);
  const int r = t & 15;
  const size_t sbase = ((size_t)(n * D_ + d) * C_) * R_ + r;
  const size_t dbase = (size_t)((d * R_ + r) * N_ + n) * C_;

  float lmx = -1e30f, rmx = -1e30f;
  {
    float vals[C_];
#pragma unroll
    for (int i = 0; i < C_; i++) {
      float v = left[sbase + (size_t)i * R_];
      vals[i] = v;
      lmx = fmaxf(lmx, v);
    }
    half8 pk[4];
#pragma unroll
    for (int i = 0; i < C_; i++) pk[i >> 3][i & 7] = (_Float16)__expf(vals[i] - lmx);
    half8* dst = (half8*)(lw + dbase);
#pragma unroll
    for (int q = 0; q < 4; q++) dst[q] = pk[q];
  }
  {
    float vals[C_];
#pragma unroll
    for (int i = 0; i < C_; i++) {
      float v = right[sbase + (size_t)i * R_];
      vals[i] = v;
      rmx = fmaxf(rmx, v);
    }
    half8 pk[4];
#pragma unroll
    for (int i = 0; i < C_; i++) pk[i >> 3][i & 7] = (_Float16)__expf(vals[i] - rmx);
    half8* dst = (half8*)(rw + dbase);
#pragma unroll
    for (int q = 0; q < 4; q++) dst[q] = pk[q];
  }
  msum[(d * R_ + r) * N_ + n] = lmx + rmx;
}

// Kernel 2: one block (256 thr = 4 waves) per (d,r).
// Phase A: unnormalized exp(logits) -> LDS in MFMA B-fragment-linear layout
//          W[(s*64+lane)*8+e] = exp(logit[d, o=lane&31, r, i, j])
//          with i = (lane>>5)*16 + (s>>2), j = (s&3)*8 + e.
//          Row sums kept per-lane; softmax denom applied as -log(sum) in epilogue.
// Phase B: C[n,o] = sum_k P[n,k] W[o,k], K=1024, via mfma_f32_32x32x16_f16.
//          A-fragment built in-register: Afrag = splat(left[row,i]) * right_octet.
__global__ __launch_bounds__(256, 2) void main_kernel(
    const float* __restrict__ logits, const _Float16* __restrict__ lw,
    const _Float16* __restrict__ rw, const float* __restrict__ msum,
    float* __restrict__ out) {
  __shared__ _Float16 Wl[64 * 64 * 8];  // 64 KB
  __shared__ float psum[4][64];
  __shared__ float msum_s[N_];

  const int bid = blockIdx.x;
  // chunked XCD swizzle: XCD x gets contiguous work ids [x*128, x*128+128)
  // so all 16 r-blocks of a given d share one XCD's L2 (output-write merging).
  const int workid = ((bid & 7) << 7) | (bid >> 3);
  const int d = workid >> 4, r = workid & 15;

  const int t = threadIdx.x;
  const int w = t >> 6, l = t & 63;
  const int o = l & 31, jb = l >> 5;

  msum_s[t] = msum[(d * R_ + r) * N_ + t];

  // ---- Phase A: exp(logits) -> Wl (wave w owns s in [w*16, w*16+16)) ----
  const float* lg = logits + ((size_t)((d * O_ + o) * R_ + r) * C_) * C_;
  float lsum = 0.f;
#pragma unroll
  for (int ii = 0; ii < 4; ii++) {
    const int i = (jb << 4) | (w << 2) | ii;
    float vv[C_];
    const float4* rp = (const float4*)(lg + i * C_);
#pragma unroll
    for (int q = 0; q < 8; q++) {
      float4 f = rp[q];
      vv[q * 4 + 0] = f.x;
      vv[q * 4 + 1] = f.y;
      vv[q * 4 + 2] = f.z;
      vv[q * 4 + 3] = f.w;
    }
#pragma unroll
    for (int q2 = 0; q2 < 4; q2++) {
      const int s = (w << 4) | (ii << 2) | q2;
      half8 hh;
#pragma unroll
      for (int p = 0; p < 8; p++) {
        float e = __expf(vv[(q2 << 3) | p]);
        lsum += e;
        hh[p] = (_Float16)e;
      }
      *(half8*)&Wl[((s << 6) | l) << 3] = hh;
    }
  }
  psum[w][l] = lsum;
  __syncthreads();
  float tot = 0.f;
#pragma unroll
  for (int ww = 0; ww < 4; ww++) tot += psum[ww][o] + psum[ww][o + 32];
  const float rlogsum = __logf(tot);

  // ---- Phase B: GEMM. wave w owns rows [w*64, w*64+64), mb in {0,1} ----
  const _Float16* lbase = lw + (size_t)((d * R_ + r) * N_) * C_;
  const _Float16* rbase = rw + (size_t)((d * R_ + r) * N_) * C_;
  half8 Lh[2][2], Rh[2][4];
#pragma unroll
  for (int mb = 0; mb < 2; mb++) {
    const int row = (w << 6) | (mb << 5) | o;  // A-row = lane&31
    const half8* lp = (const half8*)(lbase + row * C_ + (jb << 4));
    Lh[mb][0] = lp[0];
    Lh[mb][1] = lp[1];
    const half8* rp2 = (const half8*)(rbase + row * C_);
#pragma unroll
    for (int q = 0; q < 4; q++) Rh[mb][q] = rp2[q];
  }

  f32x16 acc[2];
#pragma unroll
  for (int mb = 0; mb < 2; mb++)
#pragma unroll
    for (int g = 0; g < 16; g++) acc[mb][g] = 0.f;

#pragma unroll
  for (int s = 0; s < 64; s++) {
    const half8 Bf = *(const half8*)&Wl[((s << 6) | l) << 3];  // lane-linear, conflict-free
    const int ig = s >> 2, qq = s & 3;
#pragma unroll
    for (int mb = 0; mb < 2; mb++) {
      const _Float16 Lsc = Lh[mb][ig >> 3][ig & 7];
      const half8 Ld = {Lsc, Lsc, Lsc, Lsc, Lsc, Lsc, Lsc, Lsc};
      const half8 Af = Ld * Rh[mb][qq];  // 4x v_pk_mul_f16
      acc[mb] = __builtin_amdgcn_mfma_f32_32x32x16_f16(Af, Bf, acc[mb], 0, 0, 0);
    }
  }

  // ---- Epilogue: out[n,d,o,r] = log(acc) - log(sum_exp) + lmax + rmax ----
#pragma unroll
  for (int mb = 0; mb < 2; mb++) {
#pragma unroll
    for (int g = 0; g < 16; g++) {
      const int rowt = (g & 3) + ((g >> 2) << 3) + (jb << 2);
      const int n = (w << 6) | (mb << 5) | rowt;
      const float val = __logf(acc[mb][g]) - rlogsum + msum_s[n];
      out[(((size_t)n * D_ + d) * O_ + o) * R_ + r] = val;
    }
  }
}

extern "C" void kernel_launch(void* const* d_in, const int* in_sizes, int n_in,
                              void* d_out, int out_size, void* d_ws, size_t ws_size,
                              hipStream_t stream) {
  const float* left = (const float*)d_in[0];
  const float* right = (const float*)d_in[1];
  const float* logits = (const float*)d_in[2];
  float* out = (float*)d_out;
  _Float16* lw = (_Float16*)d_ws;                                        // 16 MB
  _Float16* rw = (_Float16*)((char*)d_ws + (size_t)16 * 1024 * 1024);    // 16 MB
  float* ms = (float*)((char*)d_ws + (size_t)32 * 1024 * 1024);          // 1 MB

  prep_kernel<<<1024, 256, 0, stream>>>(left, right, lw, rw, ms);
  main_kernel<<<1024, 256, 0, stream>>>(logits, lw, rw, ms, out);
}

// Round 3
// 303.009 us; speedup vs baseline: 1.0024x; 1.0024x over previous
//
#include <hip/hip_runtime.h>

#define N_ 256
#define D_ 64
#define C_ 32
#define R_ 16
#define O_ 32

typedef _Float16 half8 __attribute__((ext_vector_type(8)));
typedef float f32x16 __attribute__((ext_vector_type(16)));

// Kernel 1: left/right prep. thread <-> (n,d,r). Reads fp32 (16 lanes cover each
// 64B line), computes max over i, writes exp(x-max) as fp16 in (d,r,n,i) layout
// (contiguous 64B per thread) + combined max sum. (Unchanged from R1 — passed.)
__global__ __launch_bounds__(256) void prep_kernel(
    const float* __restrict__ left, const float* __restrict__ right,
    _Float16* __restrict__ lw, _Float16* __restrict__ rw,
    float* __restrict__ msum) {
  const int b = blockIdx.x, t = threadIdx.x;
  const int n = ((b >> 3) << 1) | (t >> 7);
  const int d = ((b & 7) << 3) | ((t >> 4) & 7);
  const int r = t & 15;
  const size_t sbase = ((size_t)(n * D_ + d) * C_) * R_ + r;
  const size_t dbase = (size_t)((d * R_ + r) * N_ + n) * C_;

  float lmx = -1e30f, rmx = -1e30f;
  {
    float vals[C_];
#pragma unroll
    for (int i = 0; i < C_; i++) {
      float v = left[sbase + (size_t)i * R_];
      vals[i] = v;
      lmx = fmaxf(lmx, v);
    }
    half8 pk[4];
#pragma unroll
    for (int i = 0; i < C_; i++) pk[i >> 3][i & 7] = (_Float16)__expf(vals[i] - lmx);
    half8* dst = (half8*)(lw + dbase);
#pragma unroll
    for (int q = 0; q < 4; q++) dst[q] = pk[q];
  }
  {
    float vals[C_];
#pragma unroll
    for (int i = 0; i < C_; i++) {
      float v = right[sbase + (size_t)i * R_];
      vals[i] = v;
      rmx = fmaxf(rmx, v);
    }
    half8 pk[4];
#pragma unroll
    for (int i = 0; i < C_; i++) pk[i >> 3][i & 7] = (_Float16)__expf(vals[i] - rmx);
    half8* dst = (half8*)(rw + dbase);
#pragma unroll
    for (int q = 0; q < 4; q++) dst[q] = pk[q];
  }
  msum[(d * R_ + r) * N_ + n] = lmx + rmx;
}

// Kernel 2: one block (512 thr = 8 waves) per (d,r).
// W element (o,i,j) <-> fragment (s, slot, e): s = ((i&15)<<2)|(j>>3),
// slot = ((i>>4)<<5)|o, e = j&7.  (Verified mapping from R1.)
// K split into two halves by s-bit5 (i.e. i&8): half ss holds s_loc = s & 31,
// LDS only 32 KB -> 35 KB total -> better occupancy.  Half-1 global loads are
// issued before the half-0 GEMM (software pipeline).
// Each wave owns one 32-row n-tile: row = w*32 + (lane&31).
__global__ __launch_bounds__(512, 4) void main_kernel(
    const float* __restrict__ logits, const _Float16* __restrict__ lw,
    const _Float16* __restrict__ rw, const float* __restrict__ msum,
    float* __restrict__ out) {
  __shared__ _Float16 Wl[32 * 64 * 8];  // 32 KB (one K-half)
  __shared__ float psum[16][32];
  __shared__ float msum_s[N_];

  const int bid = blockIdx.x;
  // chunked XCD swizzle: all 16 r-blocks of a d share one XCD's L2.
  const int workid = ((bid & 7) << 7) | (bid >> 3);
  const int d = workid >> 4, r = workid & 15;

  const int t = threadIdx.x;
  const int w = t >> 6, l = t & 63;
  const int o = l & 31, jb = l >> 5;

  // ---- GEMM A-side fragments (tiny, issue first) ----
  const _Float16* lbase = lw + (size_t)((d * R_ + r) * N_) * C_;
  const _Float16* rbase = rw + (size_t)((d * R_ + r) * N_) * C_;
  const int row = (w << 5) | o;
  const half8* lp = (const half8*)(lbase + row * C_ + (jb << 4));
  const half8 LhA = lp[0];  // i = jb*16 + 0..7   (ss=0)
  const half8 LhB = lp[1];  // i = jb*16 + 8..15  (ss=1)
  const half8* rp2 = (const half8*)(rbase + row * C_);
  half8 Rh[4];
#pragma unroll
  for (int q = 0; q < 4; q++) Rh[q] = rp2[q];

  if (t < N_) msum_s[t] = msum[(d * R_ + r) * N_ + t];

  // ---- Phase A mapping: thread -> one (o_a, i) row of 32 logits ----
  const int o_a = t & 31, ih = t >> 5;  // ih in [0,16)
  const float* lgrow =
      logits + ((size_t)((d * O_ + o_a) * R_ + r) * C_) * C_;
  const int i0 = ((ih >> 3) << 4) | (ih & 7);  // ss=0 row
  const int slot = ((ih >> 3) << 5) | o_a;
  const int sbase_a = (ih & 7) << 2;

  float lsum = 0.f;

  // ---- A0: load + exp + store half 0 ----
  float4 v0[8];
  {
    const float4* rp = (const float4*)(lgrow + i0 * C_);
#pragma unroll
    for (int q = 0; q < 8; q++) v0[q] = rp[q];
  }
#pragma unroll
  for (int q2 = 0; q2 < 4; q2++) {
    half8 hh;
    float tmp[8] = {v0[q2 * 2].x,     v0[q2 * 2].y,     v0[q2 * 2].z,
                    v0[q2 * 2].w,     v0[q2 * 2 + 1].x, v0[q2 * 2 + 1].y,
                    v0[q2 * 2 + 1].z, v0[q2 * 2 + 1].w};
#pragma unroll
    for (int p = 0; p < 8; p++) {
      float e = __expf(tmp[p]);
      lsum += e;
      hh[p] = (_Float16)e;
    }
    *(half8*)&Wl[(((sbase_a | q2) << 6) | slot) << 3] = hh;
  }
  __syncthreads();  // (1) Wl half-0 ready

  // ---- issue A1 loads (overlap with GEMM0) ----
  float4 v1[8];
  {
    const float4* rp = (const float4*)(lgrow + (i0 + 8) * C_);
#pragma unroll
    for (int q = 0; q < 8; q++) v1[q] = rp[q];
  }

  f32x16 acc;
#pragma unroll
  for (int g = 0; g < 16; g++) acc[g] = 0.f;

  // ---- GEMM half 0: s_glob = s_loc, i-octet = s_loc>>2 in [0,8) ----
#pragma unroll
  for (int s = 0; s < 32; s++) {
    const half8 Bf = *(const half8*)&Wl[((s << 6) | l) << 3];
    const _Float16 Lsc = LhA[s >> 2];
    const half8 Ld = {Lsc, Lsc, Lsc, Lsc, Lsc, Lsc, Lsc, Lsc};
    acc = __builtin_amdgcn_mfma_f32_32x32x16_f16(Ld * Rh[s & 3], Bf, acc, 0, 0, 0);
  }
  __syncthreads();  // (2) done reading Wl half-0

  // ---- A1: exp + store half 1 ----
#pragma unroll
  for (int q2 = 0; q2 < 4; q2++) {
    half8 hh;
    float tmp[8] = {v1[q2 * 2].x,     v1[q2 * 2].y,     v1[q2 * 2].z,
                    v1[q2 * 2].w,     v1[q2 * 2 + 1].x, v1[q2 * 2 + 1].y,
                    v1[q2 * 2 + 1].z, v1[q2 * 2 + 1].w};
#pragma unroll
    for (int p = 0; p < 8; p++) {
      float e = __expf(tmp[p]);
      lsum += e;
      hh[p] = (_Float16)e;
    }
    *(half8*)&Wl[(((sbase_a | q2) << 6) | slot) << 3] = hh;
  }
  psum[ih][o_a] = lsum;
  __syncthreads();  // (3) Wl half-1 + psum ready

  // ---- GEMM half 1: s_glob = 32 + s_loc, i-octet = 8 + (s_loc>>2) ----
#pragma unroll
  for (int s = 0; s < 32; s++) {
    const half8 Bf = *(const half8*)&Wl[((s << 6) | l) << 3];
    const _Float16 Lsc = LhB[s >> 2];
    const half8 Ld = {Lsc, Lsc, Lsc, Lsc, Lsc, Lsc, Lsc, Lsc};
    acc = __builtin_amdgcn_mfma_f32_32x32x16_f16(Ld * Rh[s & 3], Bf, acc, 0, 0, 0);
  }

  // ---- softmax denom + epilogue ----
  float tot = 0.f;
#pragma unroll
  for (int k = 0; k < 16; k++) tot += psum[k][o];
  const float rlogsum = __logf(tot);

#pragma unroll
  for (int g = 0; g < 16; g++) {
    const int n = (w << 5) | ((g & 3) + ((g >> 2) << 3) + (jb << 2));
    const float val = __logf(acc[g]) - rlogsum + msum_s[n];
    out[(((size_t)n * D_ + d) * O_ + o) * R_ + r] = val;
  }
}

extern "C" void kernel_launch(void* const* d_in, const int* in_sizes, int n_in,
                              void* d_out, int out_size, void* d_ws, size_t ws_size,
                              hipStream_t stream) {
  const float* left = (const float*)d_in[0];
  const float* right = (const float*)d_in[1];
  const float* logits = (const float*)d_in[2];
  float* out = (float*)d_out;
  _Float16* lw = (_Float16*)d_ws;                                        // 16 MB
  _Float16* rw = (_Float16*)((char*)d_ws + (size_t)16 * 1024 * 1024);    // 16 MB
  float* ms = (float*)((char*)d_ws + (size_t)32 * 1024 * 1024);          // 1 MB

  prep_kernel<<<1024, 256, 0, stream>>>(left, right, lw, rw, ms);
  main_kernel<<<1024, 512, 0, stream>>>(logits, lw, rw, ms, out);
}

// Round 4
// 275.553 us; speedup vs baseline: 1.1023x; 1.0996x over previous
//
#include <hip/hip_runtime.h>

#define N_ 256
#define D_ 64
#define C_ 32
#define R_ 16
#define O_ 32

typedef _Float16 half8 __attribute__((ext_vector_type(8)));
typedef _Float16 half4 __attribute__((ext_vector_type(4)));
typedef float f32x16 __attribute__((ext_vector_type(16)));

// Kernel 1: left/right prep. UNCHANGED from R1/R3 (isolate this round's variable).
__global__ __launch_bounds__(256) void prep_kernel(
    const float* __restrict__ left, const float* __restrict__ right,
    _Float16* __restrict__ lw, _Float16* __restrict__ rw,
    float* __restrict__ msum) {
  const int b = blockIdx.x, t = threadIdx.x;
  const int n = ((b >> 3) << 1) | (t >> 7);
  const int d = ((b & 7) << 3) | ((t >> 4) & 7);
  const int r = t & 15;
  const size_t sbase = ((size_t)(n * D_ + d) * C_) * R_ + r;
  const size_t dbase = (size_t)((d * R_ + r) * N_ + n) * C_;

  float lmx = -1e30f, rmx = -1e30f;
  {
    float vals[C_];
#pragma unroll
    for (int i = 0; i < C_; i++) {
      float v = left[sbase + (size_t)i * R_];
      vals[i] = v;
      lmx = fmaxf(lmx, v);
    }
    half8 pk[4];
#pragma unroll
    for (int i = 0; i < C_; i++) pk[i >> 3][i & 7] = (_Float16)__expf(vals[i] - lmx);
    half8* dst = (half8*)(lw + dbase);
#pragma unroll
    for (int q = 0; q < 4; q++) dst[q] = pk[q];
  }
  {
    float vals[C_];
#pragma unroll
    for (int i = 0; i < C_; i++) {
      float v = right[sbase + (size_t)i * R_];
      vals[i] = v;
      rmx = fmaxf(rmx, v);
    }
    half8 pk[4];
#pragma unroll
    for (int i = 0; i < C_; i++) pk[i >> 3][i & 7] = (_Float16)__expf(vals[i] - rmx);
    half8* dst = (half8*)(rw + dbase);
#pragma unroll
    for (int q = 0; q < 4; q++) dst[q] = pk[q];
  }
  msum[(d * R_ + r) * N_ + n] = lmx + rmx;
}

// Kernel 2 v2: one block (512 thr = 8 waves) per (d,r).
// Phase A (coalesced): wave w reads whole 4KB o-slices o=4w+sl (sl=0..3),
//   64 lanes x 16B contiguous per instr. Lane l, chunk k holds logits quad
//   (o, i = 8k + (l>>3), j = 4*(l&7)..+3). Scatter into the MFMA fragment
//   layout happens via LDS writes: s = ((i&15)<<2)|(j>>3), slot=((i>>4)<<5)|o,
//   byte = (s<<10 | slot<<4 | (l&1)<<3) ^ ((s&7)<<4)   [XOR swizzle, both sides].
// Phase B: C[n,o] = sum_k P[n,k] W[o,k] (K=1024) in one 64-step pass.
// Epilogue: coalesced store to scratch laid out (d,r,n,o), OVERLAID on the
//   lw/rw regions of this same (d,r) (consumed into registers pre-barrier).
__global__ __launch_bounds__(512, 4) void main_kernel(
    const float* __restrict__ logits, const _Float16* lw, const _Float16* rw,
    const float* __restrict__ msum, float* scrA, float* scrB) {
  __shared__ __align__(16) _Float16 Wl[64 * 64 * 8];  // 64 KB
  __shared__ float psum_o[32];
  __shared__ float msum_s[N_];

  const int bid = blockIdx.x;
  const int workid = ((bid & 7) << 7) | (bid >> 3);
  const int d = workid >> 4, r = workid & 15;

  const int t = threadIdx.x;
  const int w = t >> 6, l = t & 63;
  const int o = l & 31, jb = l >> 5;

  // ---- GEMM A-side fragments (register-resident BEFORE the barrier; the
  //      barrier drains vmcnt, so the scratch overlay below is safe) ----
  const _Float16* lbase = lw + (size_t)((d * R_ + r) * N_) * C_;
  const _Float16* rbase = rw + (size_t)((d * R_ + r) * N_) * C_;
  const int row = (w << 5) | o;
  const half8* lp = (const half8*)(lbase + row * C_ + (jb << 4));
  const half8 LhA = lp[0];
  const half8 LhB = lp[1];
  const half8* rp2 = (const half8*)(rbase + row * C_);
  half8 Rh[4];
#pragma unroll
  for (int q = 0; q < 4; q++) Rh[q] = rp2[q];

  if (t < N_) msum_s[t] = msum[(d * R_ + r) * N_ + t];

  // ---- Phase A: coalesced slice loads + exp + swizzled LDS scatter ----
  float lsum[4] = {0.f, 0.f, 0.f, 0.f};
#pragma unroll
  for (int hp = 0; hp < 2; hp++) {  // two slice-pairs: bounds register pressure
    float4 v[2][4];
#pragma unroll
    for (int sp = 0; sp < 2; sp++) {
      const int sl = (hp << 1) | sp;
      const int oa = (w << 2) | sl;
      const float4* lg4 =
          (const float4*)(logits + ((size_t)((d * O_ + oa) * R_ + r) << 10));
#pragma unroll
      for (int k = 0; k < 4; k++) v[sp][k] = lg4[(k << 6) + l];
    }
#pragma unroll
    for (int sp = 0; sp < 2; sp++) {
      const int sl = (hp << 1) | sp;
      const int oa = (w << 2) | sl;
#pragma unroll
      for (int k = 0; k < 4; k++) {
        const float4 f = v[sp][k];
        const float e0 = __expf(f.x), e1 = __expf(f.y), e2 = __expf(f.z),
                    e3 = __expf(f.w);
        lsum[sl] += (e0 + e1) + (e2 + e3);
        half4 hq = {(_Float16)e0, (_Float16)e1, (_Float16)e2, (_Float16)e3};
        const int s_ = ((((k & 1) << 3) | (l >> 3)) << 2) | ((l & 7) >> 1);
        const int slot_ = ((k >> 1) << 5) | oa;
        const int byte_ =
            ((s_ << 10) | (slot_ << 4) | ((l & 1) << 3)) ^ ((s_ & 7) << 4);
        *(half4*)((char*)Wl + byte_) = hq;
      }
    }
  }
  // per-slice wave reduction -> softmax denominators
#pragma unroll
  for (int sl = 0; sl < 4; sl++) {
    float ss = lsum[sl];
#pragma unroll
    for (int off = 32; off >= 1; off >>= 1) ss += __shfl_xor(ss, off);
    if (l == 0) psum_o[(w << 2) | sl] = ss;
  }
  __syncthreads();

  const float rlogsum = __logf(psum_o[o]);

  // ---- Phase B: GEMM over 64 fragment steps ----
  f32x16 acc;
#pragma unroll
  for (int g = 0; g < 16; g++) acc[g] = 0.f;

#pragma unroll
  for (int s = 0; s < 64; s++) {
    const int byte_r = ((s << 10) | (l << 4)) ^ ((s & 7) << 4);
    const half8 Bf = *(const half8*)((const char*)Wl + byte_r);
    const int ig = s >> 2;
    const _Float16 Lsc = (ig < 8) ? LhA[ig & 7] : LhB[ig & 7];
    const half8 Ld = {Lsc, Lsc, Lsc, Lsc, Lsc, Lsc, Lsc, Lsc};
    acc = __builtin_amdgcn_mfma_f32_32x32x16_f16(Ld * Rh[s & 3], Bf, acc, 0, 0, 0);
  }

  // ---- Epilogue: coalesced store to (d,r,n,o) scratch (overlaid lw/rw) ----
  float* sb = ((w < 4) ? scrA : scrB) + ((size_t)(d * R_ + r) << 12) +
              (((w & 3) << 5) << 5) + o;
#pragma unroll
  for (int g = 0; g < 16; g++) {
    const int rowt = (g & 3) + ((g >> 2) << 3) + (jb << 2);
    const int n = (w << 5) | rowt;
    const float val = __logf(acc[g]) - rlogsum + msum_s[n];
    sb[rowt << 5] = val;
  }
}

// Kernel 3: transpose (d,r,n,o) -> out (n,d,o,r). Coalesced both sides via a
// stride-20 LDS tile. Block = (d, 8-n chunk); reads are L3-warm.
__global__ __launch_bounds__(256) void trans_kernel(const float* scrA,
                                                    const float* scrB,
                                                    float* __restrict__ out) {
  __shared__ float tile[8 * 32 * 20];  // [nl][o] rows of 20 (16 r + pad)
  const int bid = blockIdx.x;
  const int d = bid >> 5, chunk = bid & 31;
  const int n0 = chunk << 3;
  const float* src = (chunk < 16) ? scrA : scrB;
  const int t = threadIdx.x;

  {
    const int r_t = t >> 4, i16 = t & 15;
    const float* rb =
        src + ((size_t)(d * R_ + r_t) << 12) + (((chunk & 15) << 3) << 5);
#pragma unroll
    for (int k = 0; k < 4; k++) {
      const int f = (k << 4) | i16;
      const float4 v = *(const float4*)(rb + (f << 2));
      const int nl = f >> 3, o4 = (f & 7) << 2;
#pragma unroll
      for (int j = 0; j < 4; j++)
        tile[((nl << 5) | (o4 + j)) * 20 + r_t] = v[j];
    }
  }
  __syncthreads();
  {
    const int n_w = t >> 5, pos = t & 31;
    float* ob = out + (((size_t)(n0 + n_w) * D_ + d) << 9);
#pragma unroll
    for (int k = 0; k < 4; k++) {
      const int idx = (k << 5) | pos;
      const float4 v =
          *(const float4*)&tile[((n_w << 5) | (idx >> 2)) * 20 + ((pos & 3) << 2)];
      *(float4*)(ob + (idx << 2)) = v;
    }
  }
}

extern "C" void kernel_launch(void* const* d_in, const int* in_sizes, int n_in,
                              void* d_out, int out_size, void* d_ws, size_t ws_size,
                              hipStream_t stream) {
  const float* left = (const float*)d_in[0];
  const float* right = (const float*)d_in[1];
  const float* logits = (const float*)d_in[2];
  float* out = (float*)d_out;
  _Float16* lw = (_Float16*)d_ws;                                        // 16 MB
  _Float16* rw = (_Float16*)((char*)d_ws + (size_t)16 * 1024 * 1024);    // 16 MB
  float* ms = (float*)((char*)d_ws + (size_t)32 * 1024 * 1024);          // 1 MB
  float* scrA = (float*)d_ws;                       // overlays lw (post-consume)
  float* scrB = (float*)((char*)d_ws + (size_t)16 * 1024 * 1024);  // overlays rw

  prep_kernel<<<1024, 256, 0, stream>>>(left, right, lw, rw, ms);
  main_kernel<<<1024, 512, 0, stream>>>(logits, lw, rw, ms, scrA, scrB);
  trans_kernel<<<2048, 256, 0, stream>>>(scrA, scrB, out);
}